// Round 3
// baseline (77323.035 us; speedup 1.0000x reference)
//
#include <hip/hip_runtime.h>
#include <math.h>

#define BLOCK   512
#define HD      64
#define VFH     128
#define WD      5
#define NPAIR   10
#define LSDIM   16
#define LSLEN   16
#define TSN     128
#define OUTD    (WD*HD)   // 320

__device__ __forceinline__ float dpp_xor1(float x) {
    return __int_as_float(__builtin_amdgcn_mov_dpp(__float_as_int(x), 0xB1, 0xF, 0xF, false));
}
__device__ __forceinline__ float dpp_xor2(float x) {
    return __int_as_float(__builtin_amdgcn_mov_dpp(__float_as_int(x), 0x4E, 0xF, 0xF, false));
}
__device__ __forceinline__ float dot4(float4 a, float4 b) {
    return a.x*b.x + a.y*b.y + a.z*b.z + a.w*b.w;
}

// Combined-tangent LogNeuralCDE:
//   T_w = sum_q c_{w,q} * vf_out[q]   (Lie coefficients pushed through the linear JVP)
//   U_w = d1 .* (W1 @ (d0 .* (W0 @ T_w)))
//   field_block_w[o] = ls[1+w]*out[o] + der[o]*(W2_o . U_w)
// All weights register-resident; LDS holds only activation vectors.
__global__ __launch_bounds__(BLOCK, 1)
void lncde_kernel(const float* __restrict__ ts, const float* __restrict__ logsig,
                  const float* __restrict__ x0,
                  const float* __restrict__ l1w, const float* __restrict__ l1b,
                  const float* __restrict__ l2w, const float* __restrict__ l2b,
                  const float* __restrict__ w0g, const float* __restrict__ b0g,
                  const float* __restrict__ w1g, const float* __restrict__ b1g,
                  const float* __restrict__ w2g, const float* __restrict__ b2g,
                  const int* __restrict__ pairs, const int* __restrict__ nsp,
                  float* __restrict__ outp, int dataDim)
{
    __shared__ float sTs[TSN];
    __shared__ float sLs[LSLEN * LSDIM];
    __shared__ float sH0[VFH], sH1[VFH];
    __shared__ float sOut[OUTD];
    __shared__ float sT[WD * HD];      // combined tangents
    __shared__ float sDh[WD * VFH];    // d0 .* (W0 @ T_w)
    __shared__ float sU[WD * VFH];     // d1 .* (W1 @ dh)
    __shared__ float sPart[OUTD];
    __shared__ float sY[HD], sY2[HD], sK1[HD];

    const int tid  = threadIdx.x;
    const int b    = blockIdx.x;
    const int row  = tid >> 2;    // 0..127
    const int part = tid & 3;     // j-quarter
    const int gw   = tid >> 6;    // w-block for tid<320

    // ---- stage small tables into LDS ----
    for (int i = tid; i < TSN; i += BLOCK)           sTs[i] = ts[i];
    for (int i = tid; i < LSLEN * LSDIM; i += BLOCK) sLs[i] = logsig[b * LSLEN * LSDIM + i];

    // ---- weights into registers (coalesced: flat offset == tid*16 / tid*32) ----
    float4 w0r[4];   // W0[row][part*16 + 4k ..]
    #pragma unroll
    for (int k = 0; k < 4; ++k) w0r[k] = *(const float4*)(w0g + tid * 16 + 4 * k);
    float4 w1r[8];   // W1[row][part*32 + 4k ..]
    #pragma unroll
    for (int k = 0; k < 8; ++k) w1r[k] = *(const float4*)(w1g + tid * 32 + 4 * k);
    const float b0r = b0g[row];
    const float b1r = b1g[row];

    float4 w2r[32];  // W2[tid][0..127] for tid<320
    float b2r = 0.f;
    if (tid < OUTD) {
        #pragma unroll
        for (int k = 0; k < 32; ++k) w2r[k] = *(const float4*)(w2g + tid * VFH + 4 * k);
        b2r = b2g[tid];
    } else {
        #pragma unroll
        for (int k = 0; k < 32; ++k) w2r[k] = make_float4(0.f, 0.f, 0.f, 0.f);
    }

    // ---- Lie-bracket partner table for this thread's w-block ----
    int qi[4] = {0,0,0,0}, pi[4] = {0,0,0,0}; float gi[4] = {0.f,0.f,0.f,0.f};
    {
        int n = 0;
        for (int p = 0; p < NPAIR; ++p) {
            int a = pairs[2 * p] - 1, bb = pairs[2 * p + 1] - 1;
            if (a == gw && n < 4)       { qi[n] = bb; pi[n] = p; gi[n] =  1.f; ++n; }
            else if (bb == gw && n < 4) { qi[n] = a;  pi[n] = p; gi[n] = -1.f; ++n; }
        }
    }

    __syncthreads();

    // y0 = x0[b,1:] @ l1w^T + l1b
    if (tid < HD) {
        float acc = l1b[tid];
        #pragma unroll
        for (int w = 0; w < WD; ++w) acc += x0[b * dataDim + 1 + w] * l1w[tid * WD + w];
        sY[tid] = acc;
    }
    const float t0v    = sTs[0];
    const int   nsteps = nsp[0];
    const float dtv    = (sTs[TSN - 1] - t0v) / (float)nsteps;
    __syncthreads();

    auto field = [&](float t, const float* __restrict__ yv, int mode) {
        // idx = min(searchsorted(ts, t, 'left') // 8, 15)
        int cnt = 0;
        #pragma unroll
        for (int s = 64; s > 0; s >>= 1) {
            int c2 = cnt + s;
            if (c2 <= TSN && sTs[c2 - 1] < t) cnt = c2;
        }
        int il = cnt >> 3; il = il > (LSLEN - 1) ? (LSLEN - 1) : il;
        const float* ls = &sLs[il * LSDIM];

        // ---- B: h0 = tanh(W0 @ y + b0) ----
        float d0v;
        {
            float acc = 0.f;
            #pragma unroll
            for (int k = 0; k < 4; ++k) {
                int kk = (k + part) & 3;                       // bank-spread rotation
                float4 y4 = *(const float4*)&yv[part * 16 + 4 * kk];
                acc += dot4(w0r[kk], y4);
            }
            acc += dpp_xor1(acc); acc += dpp_xor2(acc);        // all 4 lanes get sum
            float h = tanhf(acc + b0r); d0v = 1.f - h * h;
            if (part == 0) sH0[row] = h;
        }
        __syncthreads();
        // ---- C: h1 = tanh(W1 @ h0 + b1) ----
        float d1v;
        {
            float acc = 0.f;
            #pragma unroll
            for (int k = 0; k < 8; ++k) {
                int kk = (k + 2 * part) & 7;
                float4 x4 = *(const float4*)&sH0[part * 32 + 4 * kk];
                acc += dot4(w1r[kk], x4);
            }
            acc += dpp_xor1(acc); acc += dpp_xor2(acc);
            float h = tanhf(acc + b1r); d1v = 1.f - h * h;
            if (part == 0) sH1[row] = h;
        }
        __syncthreads();
        // ---- D: vf_out = tanh(W2 @ h1 + b2), one row per thread ----
        float outv = 0.f, derv = 0.f;
        if (tid < OUTD) {
            float acc = 0.f;
            #pragma unroll
            for (int k = 0; k < 32; ++k) {
                float4 x4 = *(const float4*)&sH1[4 * k];       // broadcast read
                acc += dot4(w2r[k], x4);
            }
            outv = tanhf(acc + b2r); derv = 1.f - outv * outv;
            sOut[tid] = outv;
        }
        __syncthreads();
        // ---- T: combined tangent T_w = sum_n g_n*ls[6+p_n]*vf_out[q_n] ----
        if (tid < OUTD) {
            int th = tid & 63;
            float tv = gi[0] * ls[6 + pi[0]] * sOut[qi[0] * HD + th]
                     + gi[1] * ls[6 + pi[1]] * sOut[qi[1] * HD + th]
                     + gi[2] * ls[6 + pi[2]] * sOut[qi[2] * HD + th]
                     + gi[3] * ls[6 + pi[3]] * sOut[qi[3] * HD + th];
            sT[gw * HD + th] = tv;
        }
        __syncthreads();
        // ---- E: dh_w = d0 .* (W0 @ T_w) ----
        #pragma unroll
        for (int w = 0; w < WD; ++w) {
            float acc = 0.f;
            #pragma unroll
            for (int k = 0; k < 4; ++k) {
                int kk = (k + part) & 3;
                float4 x4 = *(const float4*)&sT[w * HD + part * 16 + 4 * kk];
                acc += dot4(w0r[kk], x4);
            }
            acc += dpp_xor1(acc); acc += dpp_xor2(acc);
            if (part == 0) sDh[w * VFH + row] = d0v * acc;
        }
        __syncthreads();
        // ---- F: U_w = d1 .* (W1 @ dh_w) ----
        #pragma unroll
        for (int w = 0; w < WD; ++w) {
            float acc = 0.f;
            #pragma unroll
            for (int k = 0; k < 8; ++k) {
                int kk = (k + 2 * part) & 7;
                float4 x4 = *(const float4*)&sDh[w * VFH + part * 32 + 4 * kk];
                acc += dot4(w1r[kk], x4);
            }
            acc += dpp_xor1(acc); acc += dpp_xor2(acc);
            if (part == 0) sU[w * VFH + row] = d1v * acc;
        }
        __syncthreads();
        // ---- G: per-row combine: ls[1+w]*out + der*(W2_o . U_w) ----
        if (tid < OUTD) {
            const float* up = &sU[gw * VFH];
            float acc = 0.f;
            #pragma unroll
            for (int k = 0; k < 32; ++k) {
                float4 x4 = *(const float4*)&up[4 * k];        // broadcast read
                acc += dot4(w2r[k], x4);
            }
            sPart[tid] = ls[1 + gw] * outv + derv * acc;
        }
        __syncthreads();
        // ---- H: reduce over w-blocks + Heun glue ----
        if (tid < HD) {
            float kv = sPart[tid] + sPart[HD + tid] + sPart[2 * HD + tid]
                     + sPart[3 * HD + tid] + sPart[4 * HD + tid];
            if (mode == 0) { sK1[tid] = kv; sY2[tid] = sY[tid] + dtv * kv; }
            else           { sY[tid] = sY[tid] + 0.5f * dtv * (sK1[tid] + kv); }
        }
        __syncthreads();
    };

    for (int i = 0; i < nsteps; ++i) {
        float t = t0v + (float)i * dtv;
        field(t, sY, 0);
        field(t + dtv, sY2, 1);
    }

    // epilogue: logits = yT @ l2w^T + l2b ; softmax
    if (tid == 0) {
        float lg[10];
        float mx = -3.4e38f;
        for (int l = 0; l < 10; ++l) {
            float acc = l2b[l];
            for (int h = 0; h < HD; ++h) acc += sY[h] * l2w[l * HD + h];
            lg[l] = acc; mx = fmaxf(mx, acc);
        }
        float sum = 0.f;
        for (int l = 0; l < 10; ++l) { lg[l] = expf(lg[l] - mx); sum += lg[l]; }
        float inv = 1.f / sum;
        for (int l = 0; l < 10; ++l) outp[b * 10 + l] = lg[l] * inv;
    }
}

extern "C" void kernel_launch(void* const* d_in, const int* in_sizes, int n_in,
                              void* d_out, int out_size, void* d_ws, size_t ws_size,
                              hipStream_t stream) {
    const float* ts     = (const float*)d_in[0];
    const float* logsig = (const float*)d_in[1];
    const float* x0     = (const float*)d_in[2];
    const float* l1w    = (const float*)d_in[3];
    const float* l1b    = (const float*)d_in[4];
    const float* l2w    = (const float*)d_in[5];
    const float* l2b    = (const float*)d_in[6];
    const float* w0     = (const float*)d_in[7];
    const float* b0     = (const float*)d_in[8];
    const float* w1     = (const float*)d_in[9];
    const float* b1     = (const float*)d_in[10];
    const float* w2     = (const float*)d_in[11];
    const float* b2     = (const float*)d_in[12];
    const int*   pairs  = (const int*)d_in[13];
    const int*   nsp    = (const int*)d_in[14];
    float* outp = (float*)d_out;

    const int B = in_sizes[1] / (LSLEN * LSDIM);
    const int dataDim = in_sizes[2] / (B > 0 ? B : 1);

    hipLaunchKernelGGL(lncde_kernel, dim3(B), dim3(BLOCK), 0, stream,
                       ts, logsig, x0, l1w, l1b, l2w, l2b,
                       w0, b0, w1, b1, w2, b2, pairs, nsp, outp, dataDim);
}

// Round 4
// 20212.094 us; speedup vs baseline: 3.8256x; 3.8256x over previous
//
#include <hip/hip_runtime.h>
#include <math.h>

#define BLOCK   512
#define HD      64
#define VFH     128
#define WD      5
#define NPAIR   10
#define LSDIM   16
#define LSLEN   16
#define TSN     128
#define OUTD    (WD*HD)   // 320

__device__ __forceinline__ float dpp_xor1(float x) {
    return __int_as_float(__builtin_amdgcn_mov_dpp(__float_as_int(x), 0xB1, 0xF, 0xF, false));
}
__device__ __forceinline__ float dpp_xor2(float x) {
    return __int_as_float(__builtin_amdgcn_mov_dpp(__float_as_int(x), 0x4E, 0xF, 0xF, false));
}
__device__ __forceinline__ float dot4(float4 a, float4 b) {
    return a.x*b.x + a.y*b.y + a.z*b.z + a.w*b.w;
}

// Combined-tangent LogNeuralCDE:
//   T_w = sum_q c_{w,q} * vf_out[q]   (Lie coefficients pushed through the linear JVP)
//   U_w = d1 .* (W1 @ (d0 .* (W0 @ T_w)))
//   field_block_w[o] = ls[1+w]*out[o] + der[o]*(W2_o . U_w)
// Weights register-resident with STATIC indexing only (rule #20: any runtime
// index on a register array -> scratch, which was the round-2 regression).
__global__ __launch_bounds__(BLOCK, 2)
void lncde_kernel(const float* __restrict__ ts, const float* __restrict__ logsig,
                  const float* __restrict__ x0,
                  const float* __restrict__ l1w, const float* __restrict__ l1b,
                  const float* __restrict__ l2w, const float* __restrict__ l2b,
                  const float* __restrict__ w0g, const float* __restrict__ b0g,
                  const float* __restrict__ w1g, const float* __restrict__ b1g,
                  const float* __restrict__ w2g, const float* __restrict__ b2g,
                  const int* __restrict__ pairs, const int* __restrict__ nsp,
                  float* __restrict__ outp, int dataDim)
{
    __shared__ float sTs[TSN];
    __shared__ float sLs[LSLEN * LSDIM];
    __shared__ float sH0[VFH], sH1[VFH];
    __shared__ float sOut[OUTD];
    __shared__ float sT[WD * HD];      // combined tangents
    __shared__ float sDh[WD * VFH];    // d0 .* (W0 @ T_w)
    __shared__ float sU[WD * VFH];     // d1 .* (W1 @ dh)
    __shared__ float sPart[OUTD];
    __shared__ float sY[HD], sY2[HD], sK1[HD];

    const int tid  = threadIdx.x;
    const int b    = blockIdx.x;
    const int row  = tid >> 2;    // 0..127
    const int part = tid & 3;     // j-quarter
    const int gw   = tid >> 6;    // w-block for tid<320

    // ---- stage small tables into LDS ----
    for (int i = tid; i < TSN; i += BLOCK)           sTs[i] = ts[i];
    for (int i = tid; i < LSLEN * LSDIM; i += BLOCK) sLs[i] = logsig[b * LSLEN * LSDIM + i];

    // ---- weights into registers (coalesced: flat offset == tid*16 / tid*32) ----
    float4 w0r[4];   // W0[row][part*16 + 4k ..]
    #pragma unroll
    for (int k = 0; k < 4; ++k) w0r[k] = *(const float4*)(w0g + tid * 16 + 4 * k);
    float4 w1r[8];   // W1[row][part*32 + 4k ..]
    #pragma unroll
    for (int k = 0; k < 8; ++k) w1r[k] = *(const float4*)(w1g + tid * 32 + 4 * k);
    const float b0r = b0g[row];
    const float b1r = b1g[row];

    float4 w2r[32];  // W2[tid][0..127] for tid<320
    float b2r = 0.f;
    if (tid < OUTD) {
        #pragma unroll
        for (int k = 0; k < 32; ++k) w2r[k] = *(const float4*)(w2g + tid * VFH + 4 * k);
        b2r = b2g[tid];
    } else {
        #pragma unroll
        for (int k = 0; k < 32; ++k) w2r[k] = make_float4(0.f, 0.f, 0.f, 0.f);
    }

    // ---- Lie-bracket partner constants, branchless scalars (NO arrays).
    // Lex-ordered pairs of {0..4}: off(x) = x*(9-x)/2; pair (a,b),a<b has
    // index off(a)+(b-a-1). For block w, partner n (n=0..3): q = n + (n>=w).
    // q>w  -> pair (w,q), coeff +ls[6+p]; q<w -> pair (q,w), coeff -ls[6+p].
    const int  q0 = 0 + (0 >= gw), q1 = 1 + (1 >= gw), q2 = 2 + (2 >= gw), q3 = 3 + (3 >= gw);
    #define PAIR_IDX(lo, hi) ((lo) * (9 - (lo)) / 2 + ((hi) - (lo) - 1))
    const int  p0 = (q0 > gw) ? PAIR_IDX(gw, q0) : PAIR_IDX(q0, gw);
    const int  p1 = (q1 > gw) ? PAIR_IDX(gw, q1) : PAIR_IDX(q1, gw);
    const int  p2 = (q2 > gw) ? PAIR_IDX(gw, q2) : PAIR_IDX(q2, gw);
    const int  p3 = (q3 > gw) ? PAIR_IDX(gw, q3) : PAIR_IDX(q3, gw);
    const float g0 = (q0 > gw) ? 1.f : -1.f;
    const float g1 = (q1 > gw) ? 1.f : -1.f;
    const float g2 = (q2 > gw) ? 1.f : -1.f;
    const float g3 = (q3 > gw) ? 1.f : -1.f;

    __syncthreads();

    // y0 = x0[b,1:] @ l1w^T + l1b
    if (tid < HD) {
        float acc = l1b[tid];
        #pragma unroll
        for (int w = 0; w < WD; ++w) acc += x0[b * dataDim + 1 + w] * l1w[tid * WD + w];
        sY[tid] = acc;
    }
    const float t0v    = sTs[0];
    const int   nsteps = nsp[0];
    const float dtv    = (sTs[TSN - 1] - t0v) / (float)nsteps;
    __syncthreads();

    auto field = [&](float t, const float* __restrict__ yv, int mode) {
        // idx = min(searchsorted(ts, t, 'left') // 8, 15)
        int cnt = 0;
        #pragma unroll
        for (int s = 64; s > 0; s >>= 1) {
            int c2 = cnt + s;
            if (c2 <= TSN && sTs[c2 - 1] < t) cnt = c2;
        }
        int il = cnt >> 3; il = il > (LSLEN - 1) ? (LSLEN - 1) : il;
        const float* ls = &sLs[il * LSDIM];

        // ---- B: h0 = tanh(W0 @ y + b0) ----  (LDS reads: 16-lane broadcast,
        // 4 distinct addrs/wave, <=2-way conflict = free; static reg index)
        float d0v;
        {
            float acc = 0.f;
            #pragma unroll
            for (int k = 0; k < 4; ++k) {
                float4 y4 = *(const float4*)&yv[part * 16 + 4 * k];
                acc += dot4(w0r[k], y4);
            }
            acc += dpp_xor1(acc); acc += dpp_xor2(acc);        // all 4 lanes get sum
            float h = tanhf(acc + b0r); d0v = 1.f - h * h;
            if (part == 0) sH0[row] = h;
        }
        __syncthreads();
        // ---- C: h1 = tanh(W1 @ h0 + b1) ----
        float d1v;
        {
            float acc = 0.f;
            #pragma unroll
            for (int k = 0; k < 8; ++k) {
                float4 x4 = *(const float4*)&sH0[part * 32 + 4 * k];
                acc += dot4(w1r[k], x4);
            }
            acc += dpp_xor1(acc); acc += dpp_xor2(acc);
            float h = tanhf(acc + b1r); d1v = 1.f - h * h;
            if (part == 0) sH1[row] = h;
        }
        __syncthreads();
        // ---- D: vf_out = tanh(W2 @ h1 + b2), one row per thread ----
        float outv = 0.f, derv = 0.f;
        if (tid < OUTD) {
            float acc = 0.f;
            #pragma unroll
            for (int k = 0; k < 32; ++k) {
                float4 x4 = *(const float4*)&sH1[4 * k];       // full broadcast
                acc += dot4(w2r[k], x4);
            }
            outv = tanhf(acc + b2r); derv = 1.f - outv * outv;
            sOut[tid] = outv;
        }
        __syncthreads();
        // ---- T: combined tangent T_w = sum_n g_n*ls[6+p_n]*vf_out[q_n] ----
        if (tid < OUTD) {
            int th = tid & 63;
            float tv = g0 * ls[6 + p0] * sOut[q0 * HD + th]
                     + g1 * ls[6 + p1] * sOut[q1 * HD + th]
                     + g2 * ls[6 + p2] * sOut[q2 * HD + th]
                     + g3 * ls[6 + p3] * sOut[q3 * HD + th];
            sT[gw * HD + th] = tv;
        }
        __syncthreads();
        // ---- E: dh_w = d0 .* (W0 @ T_w) ----
        #pragma unroll
        for (int w = 0; w < WD; ++w) {
            float acc = 0.f;
            #pragma unroll
            for (int k = 0; k < 4; ++k) {
                float4 x4 = *(const float4*)&sT[w * HD + part * 16 + 4 * k];
                acc += dot4(w0r[k], x4);
            }
            acc += dpp_xor1(acc); acc += dpp_xor2(acc);
            if (part == 0) sDh[w * VFH + row] = d0v * acc;
        }
        __syncthreads();
        // ---- F: U_w = d1 .* (W1 @ dh_w) ----
        #pragma unroll
        for (int w = 0; w < WD; ++w) {
            float acc = 0.f;
            #pragma unroll
            for (int k = 0; k < 8; ++k) {
                float4 x4 = *(const float4*)&sDh[w * VFH + part * 32 + 4 * k];
                acc += dot4(w1r[k], x4);
            }
            acc += dpp_xor1(acc); acc += dpp_xor2(acc);
            if (part == 0) sU[w * VFH + row] = d1v * acc;
        }
        __syncthreads();
        // ---- G: per-row combine: ls[1+w]*out + der*(W2_o . U_w) ----
        if (tid < OUTD) {
            const float* up = &sU[gw * VFH];
            float acc = 0.f;
            #pragma unroll
            for (int k = 0; k < 32; ++k) {
                float4 x4 = *(const float4*)&up[4 * k];        // broadcast read
                acc += dot4(w2r[k], x4);
            }
            sPart[tid] = ls[1 + gw] * outv + derv * acc;
        }
        __syncthreads();
        // ---- H: reduce over w-blocks + Heun glue ----
        if (tid < HD) {
            float kv = sPart[tid] + sPart[HD + tid] + sPart[2 * HD + tid]
                     + sPart[3 * HD + tid] + sPart[4 * HD + tid];
            if (mode == 0) { sK1[tid] = kv; sY2[tid] = sY[tid] + dtv * kv; }
            else           { sY[tid] = sY[tid] + 0.5f * dtv * (sK1[tid] + kv); }
        }
        __syncthreads();
    };

    for (int i = 0; i < nsteps; ++i) {
        float t = t0v + (float)i * dtv;
        field(t, sY, 0);
        field(t + dtv, sY2, 1);
    }

    // epilogue: logits = yT @ l2w^T + l2b ; softmax
    if (tid == 0) {
        float lg[10];
        float mx = -3.4e38f;
        #pragma unroll
        for (int l = 0; l < 10; ++l) {
            float acc = l2b[l];
            for (int h = 0; h < HD; ++h) acc += sY[h] * l2w[l * HD + h];
            lg[l] = acc; mx = fmaxf(mx, acc);
        }
        float sum = 0.f;
        #pragma unroll
        for (int l = 0; l < 10; ++l) { lg[l] = expf(lg[l] - mx); sum += lg[l]; }
        float inv = 1.f / sum;
        #pragma unroll
        for (int l = 0; l < 10; ++l) outp[b * 10 + l] = lg[l] * inv;
    }
}

extern "C" void kernel_launch(void* const* d_in, const int* in_sizes, int n_in,
                              void* d_out, int out_size, void* d_ws, size_t ws_size,
                              hipStream_t stream) {
    const float* ts     = (const float*)d_in[0];
    const float* logsig = (const float*)d_in[1];
    const float* x0     = (const float*)d_in[2];
    const float* l1w    = (const float*)d_in[3];
    const float* l1b    = (const float*)d_in[4];
    const float* l2w    = (const float*)d_in[5];
    const float* l2b    = (const float*)d_in[6];
    const float* w0     = (const float*)d_in[7];
    const float* b0     = (const float*)d_in[8];
    const float* w1     = (const float*)d_in[9];
    const float* b1     = (const float*)d_in[10];
    const float* w2     = (const float*)d_in[11];
    const float* b2     = (const float*)d_in[12];
    const int*   pairs  = (const int*)d_in[13];
    const int*   nsp    = (const int*)d_in[14];
    float* outp = (float*)d_out;

    const int B = in_sizes[1] / (LSLEN * LSDIM);
    const int dataDim = in_sizes[2] / (B > 0 ? B : 1);

    hipLaunchKernelGGL(lncde_kernel, dim3(B), dim3(BLOCK), 0, stream,
                       ts, logsig, x0, l1w, l1b, l2w, l2b,
                       w0, b0, w1, b1, w2, b2, pairs, nsp, outp, dataDim);
}

// Round 7
// 16422.899 us; speedup vs baseline: 4.7082x; 1.2307x over previous
//
#include <hip/hip_runtime.h>
#include <math.h>

#define BLOCK   512
#define HD      64
#define VFH     128
#define WD      5
#define NPAIR   10
#define LSDIM   16
#define LSLEN   16
#define TSN     128
#define OUTD    (WD*HD)   // 320
#define PCH     36        // padded 32-float chunk stride (144B: 16B-aligned, banks 4(p+k))
#define PADIDX(i) ((((i) >> 5) * PCH) + ((i) & 31))

using f32x4 = __attribute__((ext_vector_type(4))) float;
using f32x2 = __attribute__((ext_vector_type(2))) float;

__device__ __forceinline__ float dpp_xor1(float x) {
    return __int_as_float(__builtin_amdgcn_mov_dpp(__float_as_int(x), 0xB1, 0xF, 0xF, false));
}
__device__ __forceinline__ float dpp_xor2(float x) {
    return __int_as_float(__builtin_amdgcn_mov_dpp(__float_as_int(x), 0x4E, 0xF, 0xF, false));
}
// packed dual-fp32 FMA: acc.lo += a.lo*b.lo ; acc.hi += a.hi*b.hi
__device__ __forceinline__ void pkfma(f32x2& acc, f32x2 a, f32x2 b) {
    asm("v_pk_fma_f32 %0, %1, %2, %0" : "+v"(acc) : "v"(a), "v"(b));
}
__device__ __forceinline__ void dot4pk(f32x2& acc, f32x4 w, f32x4 x) {
    f32x2 wl = {w[0], w[1]}, wh = {w[2], w[3]};
    f32x2 xl = {x[0], x[1]}, xh = {x[2], x[3]};
    pkfma(acc, wl, xl);
    pkfma(acc, wh, xh);
}

// X-macro over the 32 W2 row chunks (named vars: rule #20, static indexing only)
#define W2_LIST(OP) OP(0) OP(1) OP(2) OP(3) OP(4) OP(5) OP(6) OP(7) \
    OP(8) OP(9) OP(10) OP(11) OP(12) OP(13) OP(14) OP(15) \
    OP(16) OP(17) OP(18) OP(19) OP(20) OP(21) OP(22) OP(23) \
    OP(24) OP(25) OP(26) OP(27) OP(28) OP(29) OP(30) OP(31)

__global__ __launch_bounds__(BLOCK, 2)
void lncde_kernel(const float* __restrict__ ts, const float* __restrict__ logsig,
                  const float* __restrict__ x0,
                  const float* __restrict__ l1w, const float* __restrict__ l1b,
                  const float* __restrict__ l2w, const float* __restrict__ l2b,
                  const float* __restrict__ w0g, const float* __restrict__ b0g,
                  const float* __restrict__ w1g, const float* __restrict__ b1g,
                  const float* __restrict__ w2g, const float* __restrict__ b2g,
                  const int* __restrict__ pairs, const int* __restrict__ nsp,
                  float* __restrict__ outp, int dataDim)
{
    __shared__ float sTs[TSN];
    __shared__ float sLs[LSLEN * LSDIM];
    __shared__ float sH0p[4 * PCH];          // padded h0
    __shared__ float sH1[VFH];
    __shared__ float sOut[OUTD];
    __shared__ float sT[WD * HD];            // combined tangents
    __shared__ float sDhp[WD * 4 * PCH];     // padded d0.*(W0@T_w)
    __shared__ float sU[WD * VFH];           // d1.*(W1@dh)
    __shared__ float sPart[OUTD];
    __shared__ float sY[HD], sY2[HD], sK1[HD];

    const int tid  = threadIdx.x;
    const int b    = blockIdx.x;
    const int row  = tid >> 2;    // 0..127
    const int part = tid & 3;     // j-quarter
    const int gw   = tid >> 6;    // w-block for tid<320
    const int rowc = (tid < OUTD) ? tid : (tid - 192);   // valid W2 row for all threads

    // ---- stage small tables into LDS ----
    for (int i = tid; i < TSN; i += BLOCK)           sTs[i] = ts[i];
    for (int i = tid; i < LSLEN * LSDIM; i += BLOCK) sLs[i] = logsig[b * LSLEN * LSDIM + i];

    // ---- weights into registers (static indexing only) ----
    f32x4 w0r[4];
    #pragma unroll
    for (int k = 0; k < 4; ++k) w0r[k] = *(const f32x4*)(w0g + tid * 16 + 4 * k);
    f32x4 w1r[8];
    #pragma unroll
    for (int k = 0; k < 8; ++k) w1r[k] = *(const f32x4*)(w1g + tid * 32 + 4 * k);
    const float b0r = b0g[row];
    const float b1r = b1g[row];
    const float b2r = b2g[rowc];

#define W2_DECL(n) f32x4 w2_##n = *(const f32x4*)(w2g + rowc * VFH + 4 * (n));
    W2_LIST(W2_DECL)

    // ---- Lie-bracket partner constants, branchless scalars (no arrays) ----
    const int  q0 = 0 + (0 >= gw), q1 = 1 + (1 >= gw), q2 = 2 + (2 >= gw), q3 = 3 + (3 >= gw);
    #define PAIR_IDX(lo, hi) ((lo) * (9 - (lo)) / 2 + ((hi) - (lo) - 1))
    const int  p0 = (q0 > gw) ? PAIR_IDX(gw, q0) : PAIR_IDX(q0, gw);
    const int  p1 = (q1 > gw) ? PAIR_IDX(gw, q1) : PAIR_IDX(q1, gw);
    const int  p2 = (q2 > gw) ? PAIR_IDX(gw, q2) : PAIR_IDX(q2, gw);
    const int  p3 = (q3 > gw) ? PAIR_IDX(gw, q3) : PAIR_IDX(q3, gw);
    const float g0 = (q0 > gw) ? 1.f : -1.f;
    const float g1 = (q1 > gw) ? 1.f : -1.f;
    const float g2 = (q2 > gw) ? 1.f : -1.f;
    const float g3 = (q3 > gw) ? 1.f : -1.f;

    __syncthreads();

    // y0 = x0[b,1:] @ l1w^T + l1b
    if (tid < HD) {
        float acc = l1b[tid];
        #pragma unroll
        for (int w = 0; w < WD; ++w) acc += x0[b * dataDim + 1 + w] * l1w[tid * WD + w];
        sY[tid] = acc;
    }
    const float t0v    = sTs[0];
    const int   nsteps = nsp[0];
    const float dtv    = (sTs[TSN - 1] - t0v) / (float)nsteps;
    __syncthreads();

    auto field = [&](float t, const float* __restrict__ yv, int mode) {
        // idx = min(searchsorted(ts, t, 'left') // 8, 15)
        int cnt = 0;
        #pragma unroll
        for (int s = 64; s > 0; s >>= 1) {
            int c2 = cnt + s;
            if (c2 <= TSN && sTs[c2 - 1] < t) cnt = c2;
        }
        int il = cnt >> 3; il = il > (LSLEN - 1) ? (LSLEN - 1) : il;
        const float* ls = &sLs[il * LSDIM];

        // ---- B: h0 = tanh(W0 @ y + b0) ----
        float d0v;
        {
            f32x2 a2 = {0.f, 0.f};
            #pragma unroll
            for (int k = 0; k < 4; ++k)
                dot4pk(a2, w0r[k], *(const f32x4*)&yv[part * 16 + 4 * k]);
            float acc = a2[0] + a2[1];
            acc += dpp_xor1(acc); acc += dpp_xor2(acc);
            float h = tanhf(acc + b0r); d0v = 1.f - h * h;
            if (part == 0) sH0p[PADIDX(row)] = h;
        }
        __syncthreads();
        // ---- C: h1 = tanh(W1 @ h0 + b1) ---- (padded reads: conflict-free)
        float d1v;
        {
            f32x2 a2 = {0.f, 0.f}, b2a = {0.f, 0.f};
            #pragma unroll
            for (int k = 0; k < 8; ++k)
                dot4pk((k & 1) ? b2a : a2, w1r[k], *(const f32x4*)&sH0p[part * PCH + 4 * k]);
            float acc = a2[0] + a2[1] + b2a[0] + b2a[1];
            acc += dpp_xor1(acc); acc += dpp_xor2(acc);
            float h = tanhf(acc + b1r); d1v = 1.f - h * h;
            if (part == 0) sH1[row] = h;
        }
        __syncthreads();
        // ---- D: vf_out = tanh(W2 @ h1 + b2), one row per thread ----
        float outv = 0.f, derv = 0.f;
        {
            f32x2 accD0 = {0.f, 0.f}, accD1 = {0.f, 0.f};
#define W2_DOTD(n) dot4pk(((n) & 1) ? accD1 : accD0, w2_##n, *(const f32x4*)&sH1[4 * (n)]);
            W2_LIST(W2_DOTD)
            if (tid < OUTD) {
                float acc = accD0[0] + accD0[1] + accD1[0] + accD1[1];
                outv = tanhf(acc + b2r); derv = 1.f - outv * outv;
                sOut[tid] = outv;
            }
        }
        __syncthreads();
        // ---- T: combined tangent T_w = sum_n g_n*ls[6+p_n]*vf_out[q_n] ----
        if (tid < OUTD) {
            int th = tid & 63;
            float tv = g0 * ls[6 + p0] * sOut[q0 * HD + th]
                     + g1 * ls[6 + p1] * sOut[q1 * HD + th]
                     + g2 * ls[6 + p2] * sOut[q2 * HD + th]
                     + g3 * ls[6 + p3] * sOut[q3 * HD + th];
            sT[gw * HD + th] = tv;
        }
        __syncthreads();
        // ---- E: dh_w = d0 .* (W0 @ T_w) ----
        #pragma unroll
        for (int w = 0; w < WD; ++w) {
            f32x2 a2 = {0.f, 0.f};
            #pragma unroll
            for (int k = 0; k < 4; ++k)
                dot4pk(a2, w0r[k], *(const f32x4*)&sT[w * HD + part * 16 + 4 * k]);
            float acc = a2[0] + a2[1];
            acc += dpp_xor1(acc); acc += dpp_xor2(acc);
            if (part == 0) sDhp[w * 4 * PCH + PADIDX(row)] = d0v * acc;
        }
        __syncthreads();
        // ---- F: U_w = d1 .* (W1 @ dh_w) ---- (padded reads: conflict-free)
        #pragma unroll
        for (int w = 0; w < WD; ++w) {
            f32x2 a2 = {0.f, 0.f}, b2a = {0.f, 0.f};
            #pragma unroll
            for (int k = 0; k < 8; ++k)
                dot4pk((k & 1) ? b2a : a2, w1r[k],
                       *(const f32x4*)&sDhp[w * 4 * PCH + part * PCH + 4 * k]);
            float acc = a2[0] + a2[1] + b2a[0] + b2a[1];
            acc += dpp_xor1(acc); acc += dpp_xor2(acc);
            if (part == 0) sU[w * VFH + row] = d1v * acc;
        }
        __syncthreads();
        // ---- G: per-row combine: ls[1+w]*out + der*(W2_o . U_w) ----
        {
            const float* up = &sU[gw * VFH];
            f32x2 accG0 = {0.f, 0.f}, accG1 = {0.f, 0.f};
#define W2_DOTG(n) dot4pk(((n) & 1) ? accG1 : accG0, w2_##n, *(const f32x4*)&up[4 * (n)]);
            if (tid < OUTD) {
                W2_LIST(W2_DOTG)
                float acc = accG0[0] + accG0[1] + accG1[0] + accG1[1];
                sPart[tid] = ls[1 + gw] * outv + derv * acc;
            }
        }
        __syncthreads();
        // ---- H: reduce over w-blocks + Heun glue ----
        if (tid < HD) {
            float kv = sPart[tid] + sPart[HD + tid] + sPart[2 * HD + tid]
                     + sPart[3 * HD + tid] + sPart[4 * HD + tid];
            if (mode == 0) { sK1[tid] = kv; sY2[tid] = sY[tid] + dtv * kv; }
            else           { sY[tid] = sY[tid] + 0.5f * dtv * (sK1[tid] + kv); }
        }
        __syncthreads();
    };

#define W2_PIN(n) asm volatile("" : "+v"(w2_##n));
    for (int i = 0; i < nsteps; ++i) {
        // pin weights in registers each iteration: volatile asm can't be
        // hoisted (kills LICM) and redefines the values (kills remat).
        W2_LIST(W2_PIN)
        #pragma unroll
        for (int k = 0; k < 4; ++k) asm volatile("" : "+v"(w0r[k]));
        #pragma unroll
        for (int k = 0; k < 8; ++k) asm volatile("" : "+v"(w1r[k]));

        float t = t0v + (float)i * dtv;
        field(t, sY, 0);
        field(t + dtv, sY2, 1);
    }

    // epilogue: logits = yT @ l2w^T + l2b ; softmax
    if (tid == 0) {
        float lg[10];
        float mx = -3.4e38f;
        #pragma unroll
        for (int l = 0; l < 10; ++l) {
            float acc = l2b[l];
            for (int h = 0; h < HD; ++h) acc += sY[h] * l2w[l * HD + h];
            lg[l] = acc; mx = fmaxf(mx, acc);
        }
        float sum = 0.f;
        #pragma unroll
        for (int l = 0; l < 10; ++l) { lg[l] = expf(lg[l] - mx); sum += lg[l]; }
        float inv = 1.f / sum;
        #pragma unroll
        for (int l = 0; l < 10; ++l) outp[b * 10 + l] = lg[l] * inv;
    }
}

extern "C" void kernel_launch(void* const* d_in, const int* in_sizes, int n_in,
                              void* d_out, int out_size, void* d_ws, size_t ws_size,
                              hipStream_t stream) {
    const float* ts     = (const float*)d_in[0];
    const float* logsig = (const float*)d_in[1];
    const float* x0     = (const float*)d_in[2];
    const float* l1w    = (const float*)d_in[3];
    const float* l1b    = (const float*)d_in[4];
    const float* l2w    = (const float*)d_in[5];
    const float* l2b    = (const float*)d_in[6];
    const float* w0     = (const float*)d_in[7];
    const float* b0     = (const float*)d_in[8];
    const float* w1     = (const float*)d_in[9];
    const float* b1     = (const float*)d_in[10];
    const float* w2     = (const float*)d_in[11];
    const float* b2     = (const float*)d_in[12];
    const int*   pairs  = (const int*)d_in[13];
    const int*   nsp    = (const int*)d_in[14];
    float* outp = (float*)d_out;

    const int B = in_sizes[1] / (LSLEN * LSDIM);
    const int dataDim = in_sizes[2] / (B > 0 ? B : 1);

    hipLaunchKernelGGL(lncde_kernel, dim3(B), dim3(BLOCK), 0, stream,
                       ts, logsig, x0, l1w, l1b, l2w, l2b,
                       w0, b0, w1, b1, w2, b2, pairs, nsp, outp, dataDim);
}